// Round 10
// baseline (462.530 us; speedup 1.0000x reference)
//
#include <hip/hip_runtime.h>
#include <stdint.h>

// Problem constants (from setup_inputs): B=8, H=256, W=256, C=16, HID=128, steps=2
#define BB 8
#define HH 256
#define WW 256
#define CC 16
#define HID 128
#define NPIX (BB*HH*WW)     // 524288
#define MTILE 64            // pixels per block (GEMM tile)
#define DSTRIDE 20          // Dpart row stride in dwords (16 ch + 4 pad)
// Fire-list capacity: count ~ Binomial(NPIX, 0.5) = 262144 +- 362 (1 sigma).
// 278528 = +45 sigma; count is in fact deterministic given the fixed keys.
#define FCAP_BLOCKS 4352
#define FCAP (FCAP_BLOCKS*MTILE)   // 278528

// ---------------- Threefry2x32 (JAX-compatible, 20 rounds) ----------------
// Verified against Random123 KAT: key=(0,0), ctr=(0,0) -> (0x6b200159, 0x99ba4efe).
__host__ __device__ __forceinline__ uint32_t rotl32(uint32_t x, int r) {
  return (x << r) | (x >> (32 - r));
}

__host__ __device__ inline void threefry2x32(uint32_t k0, uint32_t k1,
                                             uint32_t x0, uint32_t x1,
                                             uint32_t& o0, uint32_t& o1) {
  const uint32_t ks2 = k0 ^ k1 ^ 0x1BD11BDAu;
  x0 += k0; x1 += k1;
#define TF_R4(a,b,c,d) \
  x0 += x1; x1 = rotl32(x1,(a)); x1 ^= x0; \
  x0 += x1; x1 = rotl32(x1,(b)); x1 ^= x0; \
  x0 += x1; x1 = rotl32(x1,(c)); x1 ^= x0; \
  x0 += x1; x1 = rotl32(x1,(d)); x1 ^= x0;
  TF_R4(13,15,26,6)   x0 += k1;  x1 += ks2 + 1u;
  TF_R4(17,29,16,24)  x0 += ks2; x1 += k0 + 2u;
  TF_R4(13,15,26,6)   x0 += k0;  x1 += k1 + 3u;
  TF_R4(17,29,16,24)  x0 += k1;  x1 += ks2 + 4u;
  TF_R4(13,15,26,6)   x0 += ks2; x1 += k0 + 5u;
#undef TF_R4
  o0 = x0; o1 = x1;
}

// ---------------- Prepass: fire masks + compacted lists + alpha extract ----
// Fire bits are a pure function of (step key, idx) — data independent. List
// order depends on atomic scheduling (nondeterministic) but every per-pixel
// result is computed independently -> d_out is replay-invariant.
__global__ __launch_bounds__(256)
void prepass(const float* __restrict__ x,
             int* __restrict__ list0, int* __restrict__ list1,
             int* __restrict__ fidx0, int* __restrict__ fidx1,
             float* __restrict__ alphaA, int* __restrict__ counters,
             uint32_t k00, uint32_t k01, uint32_t k10, uint32_t k11) {
  const int idx  = blockIdx.x * 256 + threadIdx.x;
  const int lane = threadIdx.x & 63;
  alphaA[idx] = x[(size_t)idx * CC + 3];

  // jax_threefry_partitionable: bits[i] = o0 ^ o1 of threefry(key, 0, i)
  uint32_t lo, hi;
  threefry2x32(k00, k01, 0u, (uint32_t)idx, lo, hi);
  const float u0 = __uint_as_float(((lo ^ hi) >> 9) | 0x3f800000u) - 1.0f;
  const bool f0 = u0 > 0.5f;
  threefry2x32(k10, k11, 0u, (uint32_t)idx, lo, hi);
  const float u1 = __uint_as_float(((lo ^ hi) >> 9) | 0x3f800000u) - 1.0f;
  const bool f1 = u1 > 0.5f;

  {
    const unsigned long long m = __ballot(f0);
    int base = 0;
    if (lane == 0) base = atomicAdd(&counters[0], (int)__popcll(m));
    base = __shfl(base, 0, 64);
    const int pos = base + (int)__popcll(m & ((1ull << lane) - 1ull));
    fidx0[idx] = f0 ? pos : -1;
    if (f0) list0[pos] = idx;
  }
  {
    const unsigned long long m = __ballot(f1);
    int base = 0;
    if (lane == 0) base = atomicAdd(&counters[1], (int)__popcll(m));
    base = __shfl(base, 0, 64);
    const int pos = base + (int)__popcll(m & ((1ull << lane) - 1ull));
    fidx1[idx] = f1 ? pos : -1;
    if (f1) list1[pos] = idx;
  }
}

// ---------------- Non-firing alpha passthrough ----------------
__global__ __launch_bounds__(256)
void nf_alpha(const int* __restrict__ fidx, const float* __restrict__ aold,
              float* __restrict__ anew) {
  const int idx = blockIdx.x * 256 + threadIdx.x;
  if (fidx[idx] < 0) anew[idx] = aold[idx];
}

// ---------------- Fused step kernel (FIRING pixels only) ----------------
// Block = 256 threads (4 waves), 64 compacted pixels. Round-7 structure —
// the fp32-issue-rate-optimal version (round 9 showed v_pk_fma_f32 is
// double-pumped on gfx950: fp32 peak is fixed at 157 TF, scalar v_fmac
// already saturates it):
//  - perception -> Ys[80][64] LDS; GEMM1 wave-split over hidden with
//    wave-uniform SCALAR W0/b0 loads; GEMM2 partials in-register with scalar
//    W1 loads; cross-wave reduce via Dpart[4][64][20] LDS union (20 KB).
// FP order bitwise-identical to rounds 5-9 for firing pixels; fire01 select
// and threefry removed (fire == 1 by construction here).
__global__ __launch_bounds__(256, 4)
void step_fire(const float* __restrict__ xin,
               const float* __restrict__ W0g,
               const float* __restrict__ b0g,
               const float* __restrict__ W1g,
               const int* __restrict__ list,
               const int* __restrict__ cnt,
               float* __restrict__ xnc,        // compacted updates [FCAP][16]
               float* __restrict__ alpha_new) {
  const int count = *cnt;
  const int blk = blockIdx.x;
  if (blk * MTILE >= count) return;            // uniform early-exit

  __shared__ float Sh[80 * MTILE];   // 20480 B: Ys[80][64], then Dpart[4][64][20]

  const int t  = threadIdx.x;
  const int px = t >> 2;          // 0..63 compacted position within tile
  const int c4 = (t & 3) * 4;     // channel quarter: 0,4,8,12
  const int lp = blk * MTILE + px;            // list position
  const bool active = lp < count;
  const int lpc = active ? lp : (count - 1);  // clamp for safe loads
  const int gpx = list[lpc];
  const int bi  = gpx >> 16;      // H*W = 65536
  const int ij  = gpx & 0xFFFF;
  const int ic  = ij >> 8;
  const int jc  = ij & 0xFF;

  // 3x3 correlation weights (ANGLE=0: w1=dx, w2=dy), /8 pre-applied.
  const float DXW[3][3] = {{-0.125f, 0.0f, 0.125f},
                           {-0.25f,  0.0f, 0.25f },
                           {-0.125f, 0.0f, 0.125f}};
  const float DYW[3][3] = {{-0.125f, -0.25f, -0.125f},
                           { 0.0f,    0.0f,   0.0f  },
                           { 0.125f,  0.25f,  0.125f}};
  const float LPW[3][3] = {{0.125f, 0.25f, 0.125f},
                           {0.25f, -1.5f,  0.25f },
                           {0.125f, 0.25f, 0.125f}};
  const float L2W[3][3] = {{0.0f,   0.125f, 0.0f  },
                           {0.125f, -0.5f,  0.125f},
                           {0.0f,   0.125f, 0.0f  }};

  float ctr[4] = {0,0,0,0};
  float adx[4] = {0,0,0,0};
  float ady[4] = {0,0,0,0};
  float alp[4] = {0,0,0,0};
  float al2[4] = {0,0,0,0};

  const float* xb = xin + (size_t)bi * (HH * WW * CC);
#pragma unroll
  for (int di = -1; di <= 1; ++di) {
#pragma unroll
    for (int dj = -1; dj <= 1; ++dj) {
      const int ii = ic + di, jj = jc + dj;
      const bool ok = ((unsigned)ii < (unsigned)HH) && ((unsigned)jj < (unsigned)WW);
      float4 p = make_float4(0.f, 0.f, 0.f, 0.f);
      if (ok) p = *(const float4*)(xb + ((size_t)(ii * WW + jj) * CC + c4));
      const float wdx = DXW[di+1][dj+1], wdy = DYW[di+1][dj+1];
      const float wlp = LPW[di+1][dj+1], wl2 = L2W[di+1][dj+1];
      const float pv[4] = {p.x, p.y, p.z, p.w};
#pragma unroll
      for (int q = 0; q < 4; ++q) {
        if (di == 0 && dj == 0) ctr[q] = pv[q];
        if (wdx != 0.f) adx[q] = fmaf(pv[q], wdx, adx[q]);
        if (wdy != 0.f) ady[q] = fmaf(pv[q], wdy, ady[q]);
        if (wlp != 0.f) alp[q] = fmaf(pv[q], wlp, alp[q]);
        if (wl2 != 0.f) al2[q] = fmaf(pv[q], wl2, al2[q]);
      }
    }
  }
#pragma unroll
  for (int q = 0; q < 4; ++q) {
    Sh[(c4 + q) * MTILE + px]      = ctr[q];
    Sh[(16 + c4 + q) * MTILE + px] = adx[q];
    Sh[(32 + c4 + q) * MTILE + px] = ady[q];
    Sh[(48 + c4 + q) * MTILE + px] = alp[q];
    Sh[(64 + c4 + q) * MTILE + px] = al2[q];
  }
  __syncthreads();

  // ------- GEMM1: h[hid][px] = relu(Y @ W0 + b0), wave-split over hidden ----
  const int lane = t & 63;
  const int wid  = __builtin_amdgcn_readfirstlane(t >> 6);   // 0..3, uniform
  const float* __restrict__ wslice = W0g + wid * 32;   // W0 row-major [80][128]
  const float* __restrict__ bslice = b0g + wid * 32;

  float acc[32];
#pragma unroll
  for (int s = 0; s < 32; ++s) acc[s] = bslice[s];     // scalar loads (uniform)

#pragma unroll 4
  for (int k = 0; k < 80; ++k) {
    const float yk = Sh[k * MTILE + lane];             // ds_read_b32, bank=lane
    const float* __restrict__ wr = wslice + k * HID;   // wave-uniform address
#pragma unroll
    for (int s = 0; s < 32; ++s) acc[s] = fmaf(wr[s], yk, acc[s]);  // sgpr fmac
  }

  // ------- GEMM2 partial, in-register: dpart[c] over this wave's 32 hid -----
  float dp[16];
#pragma unroll
  for (int c = 0; c < 16; ++c) dp[c] = 0.f;
#pragma unroll 4
  for (int s = 0; s < 32; ++s) {
    const float hr = fmaxf(acc[s], 0.f);
    const float* __restrict__ w1r = W1g + (wid * 32 + s) * CC;  // wave-uniform
#pragma unroll
    for (int c = 0; c < 16; ++c) dp[c] = fmaf(hr, w1r[c], dp[c]);  // sgpr fmac
  }

  __syncthreads();      // all Ys reads complete before Dpart overwrites union

  {
    float* drow = Sh + (wid * MTILE + lane) * DSTRIDE;
#pragma unroll
    for (int q = 0; q < 4; ++q)
      *(float4*)&drow[q * 4] = make_float4(dp[4*q], dp[4*q+1], dp[4*q+2], dp[4*q+3]);
  }
  __syncthreads();

  // ------- cross-wave reduce + update + store (compacted, coalesced) --------
  float4 dsum;
  {
    const float* base = Sh + px * DSTRIDE + c4;
    float4 p0 = *(const float4*)&base[0 * MTILE * DSTRIDE];
    float4 p1 = *(const float4*)&base[1 * MTILE * DSTRIDE];
    float4 p2 = *(const float4*)&base[2 * MTILE * DSTRIDE];
    float4 p3 = *(const float4*)&base[3 * MTILE * DSTRIDE];
    dsum.x = ((p0.x + p1.x) + p2.x) + p3.x;
    dsum.y = ((p0.y + p1.y) + p2.y) + p3.y;
    dsum.z = ((p0.z + p1.z) + p2.z) + p3.z;
    dsum.w = ((p0.w + p1.w) + p2.w) + p3.w;
  }
  // fire == 1 here: xv = ctr + d (bitwise == fmaf(d, 1.0, ctr))
  const float xv0 = ctr[0] + dsum.x;
  const float xv1 = ctr[1] + dsum.y;
  const float xv2 = ctr[2] + dsum.z;
  const float xv3 = ctr[3] + dsum.w;

  if (active)
    *(float4*)&xnc[(size_t)lp * CC + c4] = make_float4(xv0, xv1, xv2, xv3);
  if (active && c4 == 0) alpha_new[gpx] = xv3;   // channel 3
}

// ---------------- Life mask + state select ----------------
// prelife from OLD alpha plane, postlife from NEW alpha plane; source of the
// updated state: compacted xnc for firing pixels, prev state otherwise.
// Also writes the next step's alpha plane (life ? alpha_new : 0).
__global__ __launch_bounds__(256)
void life_mask(const float* __restrict__ prev, const float* __restrict__ xnc,
               const int* __restrict__ fidx,
               const float* __restrict__ aA, const float* __restrict__ aB,
               float* __restrict__ aC, float* __restrict__ out) {
  const int idx = blockIdx.x * 256 + threadIdx.x;
  const int b  = idx >> 16;
  const int ij = idx & 0xFFFF;
  const int i  = ij >> 8;
  const int j  = ij & 0xFF;

  const float* pA = aA + (size_t)b * (HH * WW);
  const float* pB = aB + (size_t)b * (HH * WW);
  float m0 = 0.0f, m1 = 0.0f;   // 0 padding safe vs threshold 0.1
#pragma unroll
  for (int di = -1; di <= 1; ++di) {
    const int ii = i + di;
    if ((unsigned)ii >= (unsigned)HH) continue;
#pragma unroll
    for (int dj = -1; dj <= 1; ++dj) {
      const int jj = j + dj;
      if ((unsigned)jj >= (unsigned)WW) continue;
      const size_t o = (size_t)ii * WW + jj;
      m0 = fmaxf(m0, pA[o]);
      m1 = fmaxf(m1, pB[o]);
    }
  }
  const bool life = (m0 > 0.1f) && (m1 > 0.1f);

  const int f = fidx[idx];
  const float4* src = (f >= 0) ? (const float4*)(xnc + (size_t)f * CC)
                               : (const float4*)(prev + (size_t)idx * CC);
  float4* dst = (float4*)(out + (size_t)idx * CC);
  if (life) {
    dst[0] = src[0]; dst[1] = src[1]; dst[2] = src[2]; dst[3] = src[3];
    aC[idx] = aB[idx];
  } else {
    const float4 z = make_float4(0.0f, 0.0f, 0.0f, 0.0f);
    dst[0] = z; dst[1] = z; dst[2] = z; dst[3] = z;
    aC[idx] = 0.0f;
  }
}

// ---------------- Host launcher ----------------
extern "C" void kernel_launch(void* const* d_in, const int* in_sizes, int n_in,
                              void* d_out, int out_size, void* d_ws, size_t ws_size,
                              hipStream_t stream) {
  (void)in_sizes; (void)n_in; (void)out_size; (void)ws_size;
  const float* x  = (const float*)d_in[0];
  const float* W0 = (const float*)d_in[1];
  const float* b0 = (const float*)d_in[2];
  const float* W1 = (const float*)d_in[3];
  float* out = (float*)d_out;

  // Workspace layout (~30.5 MB, < 34.5 MB used successfully in prior rounds):
  float* xnc = (float*)d_ws;                 // FCAP*16 f32      (17.8 MB)
  float* aA  = xnc + (size_t)FCAP * CC;      // NPIX f32         ( 2.1 MB)
  float* aB  = aA + NPIX;                    // NPIX f32
  float* aC  = aB + NPIX;                    // NPIX f32
  int* fidx0 = (int*)(aC + NPIX);            // NPIX i32         ( 2.1 MB)
  int* fidx1 = fidx0 + NPIX;                 // NPIX i32
  int* list0 = fidx1 + NPIX;                 // FCAP i32         ( 1.1 MB)
  int* list1 = list0 + FCAP;                 // FCAP i32
  int* counters = list1 + FCAP;              // 2 i32

  hipMemsetAsync(counters, 0, 2 * sizeof(int), stream);

  // folded keys: threefry2x32([0,42],[0,step])
  uint32_t a0, a1, b0k, b1k;
  threefry2x32(0u, 42u, 0u, 0u, a0, a1);
  threefry2x32(0u, 42u, 0u, 1u, b0k, b1k);

  prepass<<<NPIX / 256, 256, 0, stream>>>(x, list0, list1, fidx0, fidx1,
                                          aA, counters, a0, a1, b0k, b1k);
  // step 0: state = x -> out
  nf_alpha <<<NPIX / 256, 256, 0, stream>>>(fidx0, aA, aB);
  step_fire<<<FCAP_BLOCKS, 256, 0, stream>>>(x, W0, b0, W1, list0,
                                             &counters[0], xnc, aB);
  life_mask<<<NPIX / 256, 256, 0, stream>>>(x, xnc, fidx0, aA, aB, aC, out);
  // step 1: state = out -> out
  nf_alpha <<<NPIX / 256, 256, 0, stream>>>(fidx1, aC, aB);
  step_fire<<<FCAP_BLOCKS, 256, 0, stream>>>(out, W0, b0, W1, list1,
                                             &counters[1], xnc, aB);
  life_mask<<<NPIX / 256, 256, 0, stream>>>(out, xnc, fidx1, aC, aB, aA, out);
}